// Round 2
// baseline (371.759 us; speedup 1.0000x reference)
//
#include <hip/hip_runtime.h>

// LearnableWaveletTransform: depthwise conv1d (shared filter), K=96, pad=48,
// x (64,128,4096) f32 -> (l_out, h_out) each (64,128,4097) f32.
// y_f[t] = sum_{k=0}^{95} x[t-48+k] * w_f[k]
//
// R4: attack the store path + launch count.
//  - Single kernel, grid = 8192 (one block per row). B-fragments built
//    per-lane from the 96-float filters (L1-hit); t=4096 tail column folded
//    into wave 3 (source data already staged in LDS). No init kernel, no
//    tail blocks.
//  - Line-aligned wide stores: output rows have stride 4097 floats, so for
//    row%4!=0 every 256B dword-wave store hit 2 partial 64B lines (masked
//    writes ~40% of lines). Now each wave stores 64x float4 (1KB contiguous)
//    SHIFTED by c=row&3 so all float4s are 16B-aligned and interior lines
//    are full. A c-dword carry in the bounce window stitches phase
//    boundaries; <=3 head/tail dwords per wave stored scalar.
//  - Bounce skew phi(j)=j+8*(j>>5): MFMA scatter stays conflict-free
//    (bank = 8q+8r+s + const), float4 readback is <=2-way (free).
// LDS 18.8 KB -> 8 blocks/CU. Accum fp32; absmax ~0.03 << 0.117.

#define KW    96
#define PADW  48
#define T_IN  4096
#define T_OUT 4097
#define ROWS  8192           // 64*128
#define BLOCK 256
#define NF4   1056           // staged float4s per row: covers x[-48 .. 4176)
#define XSH   (NF4 * 4)      // 4224 bf16 elements
#define BSL   324            // skewed dword slots per (wave,filter) window

typedef __attribute__((ext_vector_type(8))) short short8;
typedef __attribute__((ext_vector_type(4))) float f32x4;
typedef __attribute__((ext_vector_type(4))) unsigned int uint4v;

__device__ __forceinline__ unsigned short f2bf(float v) {
    unsigned u = __builtin_bit_cast(unsigned, v);
    u += 0x7FFFu + ((u >> 16) & 1u);      // RNE (inputs are finite gaussians)
    return (unsigned short)(u >> 16);
}
__device__ __forceinline__ float bf2f(unsigned short b) {
    return __builtin_bit_cast(float, ((unsigned)b) << 16);
}

__global__ __launch_bounds__(BLOCK, 4) void lwt_main(
    const float* __restrict__ x,
    const float* __restrict__ hw,
    const float* __restrict__ lw,
    float* __restrict__ out_l,
    float* __restrict__ out_h)
{
    __shared__ alignas(16) unsigned short xs[XSH];     // 8448 B
    __shared__ float bounce[4][2][BSL];                // 10368 B
    const int bid  = blockIdx.x;
    const int tid  = threadIdx.x;
    const int lane = tid & 63;
    const int wv   = tid >> 6;

    // ---- per-lane B fragments, built from the filters directly ----
    // B[k][n] = w_f[k-s], n = f*8+s. Lane holds chunks cc=0..3:
    // element j of chunk cc is B[k = 32cc + 8q + j][n = lane&15].
    const int q  = lane >> 4;
    const int nB = lane & 15;
    const int sB = nB & 7;
    const float* wf = (nB >> 3) ? hw : lw;
    short8 bfr0, bfr1, bfr2, bfr3;
#define BUILD_BF(dst, cc)                                                   \
    {                                                                       \
        uint4v u;                                                           \
        _Pragma("unroll")                                                   \
        for (int jj = 0; jj < 4; ++jj) {                                    \
            const int k0 = 32 * (cc) + 8 * q + 2 * jj;                      \
            const int ka = k0 - sB, kb = k0 + 1 - sB;                       \
            const unsigned ba = (ka >= 0 && ka < KW) ? (unsigned)f2bf(wf[ka]) : 0u; \
            const unsigned bb = (kb >= 0 && kb < KW) ? (unsigned)f2bf(wf[kb]) : 0u; \
            u[jj] = ba | (bb << 16);                                        \
        }                                                                   \
        dst = __builtin_bit_cast(short8, u);                                \
    }
    BUILD_BF(bfr0, 0)
    BUILD_BF(bfr1, 1)
    BUILD_BF(bfr2, 2)
    BUILD_BF(bfr3, 3)
#undef BUILD_BF

    // ---- stage x[-48 .. 4176) as bf16 into LDS (zero OOB) ----
    const float* xrow = x + (size_t)bid * T_IN;
    for (int i = tid; i < NF4; i += BLOCK) {
        const int g = 4 * i - PADW;
        float4 v = make_float4(0.f, 0.f, 0.f, 0.f);
        if (g >= 0 && g < T_IN) v = *(const float4*)(xrow + g);
        ushort4 u;
        u.x = f2bf(v.x); u.y = f2bf(v.y); u.z = f2bf(v.z); u.w = f2bf(v.w);
        *(ushort4*)(xs + 4 * i) = u;
    }
    __syncthreads();     // the ONLY barrier

    // ---- per-wave: 4 phases x (2 MFMA tiles -> bounce -> aligned stores) --
    const int m   = nB;               // A-operand row
    const int sD  = nB & 7;           // D col -> shift
    const int fD  = nB >> 3;          // D col -> filter
    const int cpos = bid & 3;         // carry count; O mod 4 == cpos
    const size_t O = (size_t)bid * T_OUT + (size_t)wv * 1024;
    const int phi4 = 4 * lane + 8 * ((4 * lane) >> 5);   // skewed b128 slot
    const short8* ap = (const short8*)xs;                // 16-B granules
    float* bw_s = &bounce[wv][fD][0];                    // scatter target
    float* opl  = out_l + O - cpos;                      // 16B-aligned bases
    float* oph  = out_h + O - cpos;

    #pragma unroll 1
    for (int ph = 0; ph < 4; ++ph) {
        #pragma unroll
        for (int it = 0; it < 2; ++it) {
            const int tile = wv * 8 + ph * 2 + it;
            const int ga0 = tile * 16 + m + q;    // + 4c per chunk
            f32x4 acc = {0.f, 0.f, 0.f, 0.f};
            acc = __builtin_amdgcn_mfma_f32_16x16x32_bf16(ap[ga0     ], bfr0, acc, 0, 0, 0);
            acc = __builtin_amdgcn_mfma_f32_16x16x32_bf16(ap[ga0 +  4], bfr1, acc, 0, 0, 0);
            acc = __builtin_amdgcn_mfma_f32_16x16x32_bf16(ap[ga0 +  8], bfr2, acc, 0, 0, 0);
            acc = __builtin_amdgcn_mfma_f32_16x16x32_bf16(ap[ga0 + 12], bfr3, acc, 0, 0, 0);
            // D[row = q*4 + r][col = nB] -> i0 = it*128 + 32q + 8r + sD
            #pragma unroll
            for (int r = 0; r < 4; ++r) {
                const int i0 = it * 128 + 32 * q + 8 * r + sD;
                const int j  = cpos + i0;               // window position
                bw_s[j + 8 * (j >> 5)] = acc[r];        // conflict-free
            }
        }
        // wave-local aligned stores, both filters (no barrier needed)
        const bool skip0 = (cpos != 0) && (ph == 0) && (lane == 0);
        #pragma unroll
        for (int f = 0; f < 2; ++f) {
            float* bw = &bounce[wv][f][0];
            float* op = f ? oph : opl;
            const float4 v = *(const float4*)&bw[phi4];
            if (!skip0) *(float4*)(op + 256 * ph + 4 * lane) = v;
            if (cpos != 0) {
                float* orow = (f ? out_h : out_l) + O;
                if (ph == 0 && lane < 4 - cpos) orow[lane] = bw[cpos + lane];
                if (ph == 3 && lane < cpos)     orow[1024 - cpos + lane] = bw[320 + lane];
                if (ph < 3 && lane < cpos)      bw[lane] = bw[320 + lane];   // carry
            }
        }
    }

    // ---- tail column t=4096 (taps k<48 in-bounds), from staged LDS ----
    if (wv == 3) {
        float al = 0.f, ah = 0.f;
        if (lane < PADW) {
            const float xv = bf2f(xs[T_IN + lane]);   // x[4048+lane]
            al = xv * lw[lane];
            ah = xv * hw[lane];
        }
        #pragma unroll
        for (int off = 32; off > 0; off >>= 1) {
            al += __shfl_down(al, off);
            ah += __shfl_down(ah, off);
        }
        if (lane == 0) {
            const size_t o = (size_t)bid * T_OUT + T_IN;
            out_l[o] = al;
            out_h[o] = ah;
        }
    }
}

extern "C" void kernel_launch(void* const* d_in, const int* in_sizes, int n_in,
                              void* d_out, int out_size, void* d_ws, size_t ws_size,
                              hipStream_t stream) {
    const float* x  = (const float*)d_in[0];
    const float* hw = (const float*)d_in[1];  // h_w (96)
    const float* lw = (const float*)d_in[2];  // l_w (96)
    float* out_l = (float*)d_out;             // l_outs first (return order)
    float* out_h = out_l + (size_t)ROWS * T_OUT;

    lwt_main<<<ROWS, BLOCK, 0, stream>>>(x, hw, lw, out_l, out_h);
}